// Round 1
// baseline (418.503 us; speedup 1.0000x reference)
//
#include <hip/hip_runtime.h>

#define NTOK_MAX 16384
#define DOUT 1024
#define BM 64
#define BN 64
#define BK 32
#define LPAD 4

// ---------------------------------------------------------------------------
// Kernel 1: classify tokens into 3 cluster buckets (wave-aggregated atomics).
// bucket[c*N + pos] = token position n. cnt[c] = number of tokens in cluster c.
// ---------------------------------------------------------------------------
__global__ __launch_bounds__(256) void classify_kernel(
    const int* __restrict__ idx, int* __restrict__ cnt,
    int* __restrict__ bucket, int N) {
  int n = blockIdx.x * blockDim.x + threadIdx.x;
  int lane = threadIdx.x & 63;
  int c = -1;
  if (n < N) {
    int v = idx[n];
    c = (v < 20000) ? 0 : ((v < 40000) ? 1 : 2);
  }
#pragma unroll
  for (int k = 0; k < 3; ++k) {
    unsigned long long m = __ballot(c == k);
    if (c == k) {
      int leader = __ffsll((unsigned long long)m) - 1;
      int base = 0;
      if (lane == leader) base = atomicAdd(&cnt[k], (int)__popcll(m));
      base = __shfl(base, leader);
      int rank = (int)__popcll(m & ((1ull << (unsigned)lane) - 1ull));
      bucket[k * N + base + rank] = n;
    }
  }
}

// ---------------------------------------------------------------------------
// Kernel 2: per-cluster GEMM.  out[n, d] = sum_k emb[local_n, k] * w[d, k]
//   M = cnt[c] tokens (rows via bucket), N = DOUT, K = h.
// Tile 64x64, BK=32, fp32 vector FMA. LDS stored K-major (As[k][m]) so the
// inner loop reads float4 (ds_read_b128) per operand: 2 b128 + 16 fma / k.
// ---------------------------------------------------------------------------
__global__ __launch_bounds__(256) void gemm_cluster(
    const float* __restrict__ emb, const float* __restrict__ w,
    const int* __restrict__ idx, const int* __restrict__ cnt,
    const int* __restrict__ bucket, float* __restrict__ out,
    int h, int lo) {
  const int count = *cnt;
  const int m0 = blockIdx.y * BM;
  if (m0 >= count) return;
  const int n0 = blockIdx.x * BN;

  __shared__ float As[BK][BM + LPAD];
  __shared__ float Bs[BK][BN + LPAD];
  __shared__ int rowLocal[BM];  // emb row per tile-row (0 if invalid)
  __shared__ int rowTok[BM];    // output token per tile-row (-1 if invalid)

  const int tid = threadIdx.x;

  if (tid < BM) {
    int m = m0 + tid;
    int local = 0, tok = -1;
    if (m < count) {
      tok = bucket[m];
      local = idx[tok] - lo;
    }
    rowLocal[tid] = local;
    rowTok[tid] = tok;
  }
  __syncthreads();

  const int kgrp = tid & 7;   // 8 threads * float4 = 32 k
  const int rgrp = tid >> 3;  // 32 rows per pass

  const int tx = tid & 15;    // output col group (4 cols each)
  const int ty = tid >> 4;    // output row group (4 rows each)

  float acc[4][4] = {};

  for (int k0 = 0; k0 < h; k0 += BK) {
    __syncthreads();
    // ---- stage A (gathered emb rows), transposed into As[k][m] ----
#pragma unroll
    for (int rr = 0; rr < BM; rr += 32) {
      int r = rgrp + rr;
      const float4 v = *(const float4*)&emb[(size_t)rowLocal[r] * h + k0 + kgrp * 4];
      As[kgrp * 4 + 0][r] = v.x;
      As[kgrp * 4 + 1][r] = v.y;
      As[kgrp * 4 + 2][r] = v.z;
      As[kgrp * 4 + 3][r] = v.w;
    }
    // ---- stage B (w rows), transposed into Bs[k][n] ----
#pragma unroll
    for (int rr = 0; rr < BN; rr += 32) {
      int r = rgrp + rr;
      const float4 v = *(const float4*)&w[(size_t)(n0 + r) * h + k0 + kgrp * 4];
      Bs[kgrp * 4 + 0][r] = v.x;
      Bs[kgrp * 4 + 1][r] = v.y;
      Bs[kgrp * 4 + 2][r] = v.z;
      Bs[kgrp * 4 + 3][r] = v.w;
    }
    __syncthreads();
    // ---- compute ----
#pragma unroll
    for (int k = 0; k < BK; ++k) {
      const float4 av = *(const float4*)&As[k][ty * 4];
      const float4 bv = *(const float4*)&Bs[k][tx * 4];
      const float a[4] = {av.x, av.y, av.z, av.w};
      const float b[4] = {bv.x, bv.y, bv.z, bv.w};
#pragma unroll
      for (int i = 0; i < 4; ++i)
#pragma unroll
        for (int j = 0; j < 4; ++j) acc[i][j] = fmaf(a[i], b[j], acc[i][j]);
    }
  }

  // ---- store ----
  const int dcol = n0 + tx * 4;
#pragma unroll
  for (int i = 0; i < 4; ++i) {
    int tok = rowTok[ty * 4 + i];
    if (tok >= 0) {
      float4 v = make_float4(acc[i][0], acc[i][1], acc[i][2], acc[i][3]);
      *(float4*)&out[(size_t)tok * DOUT + dcol] = v;
    }
  }
}

extern "C" void kernel_launch(void* const* d_in, const int* in_sizes, int n_in,
                              void* d_out, int out_size, void* d_ws, size_t ws_size,
                              hipStream_t stream) {
  const int* idx = (const int*)d_in[0];
  const float* emb0 = (const float*)d_in[1];
  const float* w0 = (const float*)d_in[2];
  const float* emb1 = (const float*)d_in[3];
  const float* w1 = (const float*)d_in[4];
  const float* emb2 = (const float*)d_in[5];
  const float* w2 = (const float*)d_in[6];
  float* out = (float*)d_out;

  const int N = in_sizes[0];  // 16384

  int* cnt = (int*)d_ws;       // 3 counters (padded to 16 ints)
  int* bucket = cnt + 16;      // 3 * N token ids

  hipMemsetAsync(cnt, 0, 3 * sizeof(int), stream);
  classify_kernel<<<(N + 255) / 256, 256, 0, stream>>>(idx, cnt, bucket, N);

  dim3 grid(DOUT / BN, (N + BM - 1) / BM);
  gemm_cluster<<<grid, 256, 0, stream>>>(emb0, w0, idx, cnt + 0, bucket + 0 * N, out, 1024, 0);
  gemm_cluster<<<grid, 256, 0, stream>>>(emb1, w1, idx, cnt + 1, bucket + 1 * N, out, 256, 20000);
  gemm_cluster<<<grid, 256, 0, stream>>>(emb2, w2, idx, cnt + 2, bucket + 2 * N, out, 64, 40000);
}

// Round 2
// 229.788 us; speedup vs baseline: 1.8213x; 1.8213x over previous
//
#include <hip/hip_runtime.h>
#include <stdint.h>

#define DOUT 1024
#define NMAX 16384

typedef __attribute__((ext_vector_type(8))) short short8;
typedef __attribute__((ext_vector_type(4))) float floatx4;

__device__ __forceinline__ unsigned short f2bf(float f) {
  union { float f; uint32_t u; } v;
  v.f = f;
  return (unsigned short)((v.u + 0x7FFFu + ((v.u >> 16) & 1u)) >> 16);  // RNE
}

// ---------------------------------------------------------------------------
// classify: bucket token positions per cluster (wave-aggregated atomics).
// bucket[c*NMAX+p] = token n ; blocal[c*NMAX+p] = emb-local row
// ---------------------------------------------------------------------------
__global__ __launch_bounds__(256) void classify_kernel(
    const int* __restrict__ idx, int* __restrict__ cnt,
    int* __restrict__ bucket, int* __restrict__ blocal, int N) {
  int n = blockIdx.x * 256 + threadIdx.x;
  int lane = threadIdx.x & 63;
  int c = -1, v = 0;
  if (n < N) {
    v = idx[n];
    c = (v < 20000) ? 0 : ((v < 40000) ? 1 : 2);
  }
#pragma unroll
  for (int k = 0; k < 3; ++k) {
    unsigned long long m = __ballot(c == k);
    if (c == k) {
      int leader = __ffsll((unsigned long long)m) - 1;
      int base = 0;
      if (lane == leader) base = atomicAdd(&cnt[k], (int)__popcll(m));
      base = __shfl(base, leader);
      int rank = (int)__popcll(m & ((1ull << (unsigned)lane) - 1ull));
      int lo = (k == 0) ? 0 : (k == 1) ? 20000 : 40000;
      bucket[k * NMAX + base + rank] = n;
      blocal[k * NMAX + base + rank] = v - lo;
    }
  }
}

// ---------------------------------------------------------------------------
// fp32 -> bf16 (vectorized x4)
// ---------------------------------------------------------------------------
__global__ __launch_bounds__(256) void cvt_kernel(
    const float* __restrict__ src, unsigned short* __restrict__ dst, int n4) {
  int i = blockIdx.x * 256 + threadIdx.x;
  if (i < n4) {
    float4 v = ((const float4*)src)[i];
    ushort4 o;
    o.x = f2bf(v.x); o.y = f2bf(v.y); o.z = f2bf(v.z); o.w = f2bf(v.w);
    ((ushort4*)dst)[i] = o;
  }
}

// ---------------------------------------------------------------------------
// gather used emb rows (fp32) -> compacted bf16 matrix Acomp[count][h]
// ---------------------------------------------------------------------------
__global__ __launch_bounds__(256) void gather_kernel(
    const float* __restrict__ emb, const int* __restrict__ blocal,
    const int* __restrict__ cnt, unsigned short* __restrict__ acomp,
    int hshift) {  // h = 1<<hshift
  const int count = *cnt;
  const int h4s = hshift - 2;            // log2(float4s per row)
  const int total = count << h4s;
  for (int i = blockIdx.x * 256 + threadIdx.x; i < total; i += gridDim.x * 256) {
    int row = i >> h4s;
    int k4 = i & ((1 << h4s) - 1);
    int loc = blocal[row];
    float4 v = ((const float4*)(emb + ((size_t)loc << hshift)))[k4];
    ushort4 o;
    o.x = f2bf(v.x); o.y = f2bf(v.y); o.z = f2bf(v.z); o.w = f2bf(v.w);
    ((ushort4*)(acomp + ((size_t)row << hshift)))[k4] = o;
  }
}

// ---------------------------------------------------------------------------
// Per-cluster bf16 MFMA GEMM (m97 structure).
//   out[tok, n] = sum_k Acomp[m, k] * Wb[n, k]
// 128x128 tile, BK=32, 4 waves each owning a 64x64 quadrant as 4x4 MFMA
// 16x16x32 tiles. Staging via global_load_lds width=16 (LDS rows = 64B,
// linear in lane order -- required by the wave-uniform-base DMA).
// ---------------------------------------------------------------------------
template <int H>
__global__ __launch_bounds__(256) void gemm_mfma(
    const unsigned short* __restrict__ A,  // [NMAX][H] bf16 compacted
    const unsigned short* __restrict__ B,  // [DOUT][H] bf16 weights
    const int* __restrict__ cnt, const int* __restrict__ bucket,
    float* __restrict__ out) {
  const int count = *cnt;
  const int m0 = blockIdx.y * 128;
  if (m0 >= count) return;
  const int n0 = blockIdx.x * 128;

  __shared__ __align__(16) unsigned short As[128 * 32];  // [row][k], 64B rows
  __shared__ __align__(16) unsigned short Bs[128 * 32];
  __shared__ int rowTok[128];

  const int tid = threadIdx.x;
  const int wave = tid >> 6;
  const int lane = tid & 63;
  const int quad = lane >> 4;
  const int l16 = lane & 15;
  const int wm = wave & 1;   // quadrant row
  const int wn = wave >> 1;  // quadrant col

  if (tid < 128) {
    int m = m0 + tid;
    rowTok[tid] = (m < count) ? bucket[m] : -1;
  }

  floatx4 acc[4][4];
#pragma unroll
  for (int i = 0; i < 4; ++i)
#pragma unroll
    for (int j = 0; j < 4; ++j) acc[i][j] = (floatx4){0.f, 0.f, 0.f, 0.f};

  const char* Ab = (const char*)A;
  const char* Bb = (const char*)B;
  const int row_lo = tid >> 2;   // 0..63
  const int ck = tid & 3;        // 16B chunk within 64B row

  for (int k0 = 0; k0 < H; k0 += 32) {
    __syncthreads();
#pragma unroll
    for (int p = 0; p < 2; ++p) {
      const int row = p * 64 + row_lo;
      const void* ga = Ab + ((size_t)(m0 + row) * H + k0) * 2 + ck * 16;
      const void* gb = Bb + ((size_t)(n0 + row) * H + k0) * 2 + ck * 16;
      void* la = (char*)As + (p * 4096 + wave * 1024);  // wave-uniform base
      void* lb = (char*)Bs + (p * 4096 + wave * 1024);
      __builtin_amdgcn_global_load_lds(
          (const __attribute__((address_space(1))) void*)ga,
          (__attribute__((address_space(3))) void*)la, 16, 0, 0);
      __builtin_amdgcn_global_load_lds(
          (const __attribute__((address_space(1))) void*)gb,
          (__attribute__((address_space(3))) void*)lb, 16, 0, 0);
    }
    __syncthreads();

    short8 af[4], bf[4];
#pragma unroll
    for (int mi = 0; mi < 4; ++mi)
      af[mi] = *(const short8*)&As[(wm * 64 + mi * 16 + l16) * 32 + quad * 8];
#pragma unroll
    for (int ni = 0; ni < 4; ++ni)
      bf[ni] = *(const short8*)&Bs[(wn * 64 + ni * 16 + l16) * 32 + quad * 8];
#pragma unroll
    for (int mi = 0; mi < 4; ++mi)
#pragma unroll
      for (int ni = 0; ni < 4; ++ni)
        acc[mi][ni] = __builtin_amdgcn_mfma_f32_16x16x32_bf16(
            af[mi], bf[ni], acc[mi][ni], 0, 0, 0);
  }

  // epilogue: scatter rows to out[tok][*]  (C/D: col=lane&15, row=quad*4+reg)
  const int colBase = n0 + wn * 64 + l16;
#pragma unroll
  for (int mi = 0; mi < 4; ++mi) {
#pragma unroll
    for (int r = 0; r < 4; ++r) {
      int tok = rowTok[wm * 64 + mi * 16 + quad * 4 + r];
      if (tok >= 0) {
        float* o = out + (size_t)tok * DOUT + colBase;
#pragma unroll
        for (int ni = 0; ni < 4; ++ni) o[ni * 16] = acc[mi][ni][r];
      }
    }
  }
}

extern "C" void kernel_launch(void* const* d_in, const int* in_sizes, int n_in,
                              void* d_out, int out_size, void* d_ws, size_t ws_size,
                              hipStream_t stream) {
  const int* idx = (const int*)d_in[0];
  const float* emb0 = (const float*)d_in[1];
  const float* w0 = (const float*)d_in[2];
  const float* emb1 = (const float*)d_in[3];
  const float* w1 = (const float*)d_in[4];
  const float* emb2 = (const float*)d_in[5];
  const float* w2 = (const float*)d_in[6];
  float* out = (float*)d_out;
  const int N = in_sizes[0];  // 16384

  // ---- workspace layout ----
  char* ws = (char*)d_ws;
  int* cnt = (int*)ws;                              // 64 B
  int* bucket = (int*)(ws + 1024);                  // 3*NMAX ints
  int* blocal = bucket + 3 * NMAX;                  // 3*NMAX ints
  size_t off = 1024 + (size_t)6 * NMAX * 4;         // = 394240
  off = (off + 255) & ~(size_t)255;
  unsigned short* wb0 = (unsigned short*)(ws + off); off += (size_t)DOUT * 1024 * 2;
  unsigned short* wb1 = (unsigned short*)(ws + off); off += (size_t)DOUT * 256 * 2;
  unsigned short* wb2 = (unsigned short*)(ws + off); off += (size_t)DOUT * 64 * 2;
  off = (off + 255) & ~(size_t)255;
  unsigned short* a0 = (unsigned short*)(ws + off); off += (size_t)NMAX * 1024 * 2;
  unsigned short* a1 = (unsigned short*)(ws + off); off += (size_t)NMAX * 256 * 2;
  unsigned short* a2 = (unsigned short*)(ws + off); off += (size_t)NMAX * 64 * 2;

  hipMemsetAsync(cnt, 0, 16 * sizeof(int), stream);
  classify_kernel<<<(N + 255) / 256, 256, 0, stream>>>(idx, cnt, bucket, blocal, N);

  cvt_kernel<<<(DOUT * 1024 / 4 + 255) / 256, 256, 0, stream>>>(w0, wb0, DOUT * 1024 / 4);
  cvt_kernel<<<(DOUT * 256 / 4 + 255) / 256, 256, 0, stream>>>(w1, wb1, DOUT * 256 / 4);
  cvt_kernel<<<(DOUT * 64 / 4 + 255) / 256, 256, 0, stream>>>(w2, wb2, DOUT * 64 / 4);

  gather_kernel<<<1024, 256, 0, stream>>>(emb0, blocal + 0 * NMAX, cnt + 0, a0, 10);
  gather_kernel<<<512, 256, 0, stream>>>(emb1, blocal + 1 * NMAX, cnt + 1, a1, 8);
  gather_kernel<<<256, 256, 0, stream>>>(emb2, blocal + 2 * NMAX, cnt + 2, a2, 6);

  dim3 grid(DOUT / 128, NMAX / 128);
  gemm_mfma<1024><<<grid, 256, 0, stream>>>(a0, wb0, cnt + 0, bucket + 0 * NMAX, out);
  gemm_mfma<256><<<grid, 256, 0, stream>>>(a1, wb1, cnt + 1, bucket + 1 * NMAX, out);
  gemm_mfma<64><<<grid, 256, 0, stream>>>(a2, wb2, cnt + 2, bucket + 2 * NMAX, out);
}

// Round 3
// 213.754 us; speedup vs baseline: 1.9579x; 1.0750x over previous
//
#include <hip/hip_runtime.h>
#include <stdint.h>

#define DOUT 1024
#define NMAX 16384

typedef __attribute__((ext_vector_type(8))) short short8;
typedef __attribute__((ext_vector_type(4))) float floatx4;

__device__ __forceinline__ unsigned short f2bf(float f) {
  union { float f; uint32_t u; } v;
  v.f = f;
  return (unsigned short)((v.u + 0x7FFFu + ((v.u >> 16) & 1u)) >> 16);  // RNE
}

// ---------------------------------------------------------------------------
// Fused kernel A: classify tokens (blocks 0..63) + convert all weights to
// bf16 (blocks 64..). Independent work, one dispatch.
// ---------------------------------------------------------------------------
__global__ __launch_bounds__(256) void classify_cvt_kernel(
    const int* __restrict__ idx, int* __restrict__ cnt,
    int* __restrict__ bucket, int* __restrict__ blocal, int N,
    const float* __restrict__ w0, const float* __restrict__ w1,
    const float* __restrict__ w2, unsigned short* __restrict__ wb0,
    unsigned short* __restrict__ wb1, unsigned short* __restrict__ wb2) {
  if (blockIdx.x < 64) {
    int n = blockIdx.x * 256 + threadIdx.x;
    int lane = threadIdx.x & 63;
    int c = -1, v = 0;
    if (n < N) {
      v = idx[n];
      c = (v < 20000) ? 0 : ((v < 40000) ? 1 : 2);
    }
#pragma unroll
    for (int k = 0; k < 3; ++k) {
      unsigned long long m = __ballot(c == k);
      if (c == k) {
        int leader = __ffsll((unsigned long long)m) - 1;
        int base = 0;
        if (lane == leader) base = atomicAdd(&cnt[k], (int)__popcll(m));
        base = __shfl(base, leader);
        int rank = (int)__popcll(m & ((1ull << (unsigned)lane) - 1ull));
        int lo = (k == 0) ? 0 : (k == 1) ? 20000 : 40000;
        bucket[k * NMAX + base + rank] = n;
        blocal[k * NMAX + base + rank] = v - lo;
      }
    }
  } else {
    // weight conversion: 344064 ushort4 units total
    int i = (blockIdx.x - 64) * 256 + threadIdx.x;
    if (i >= 344064) return;
    const float4* src;
    ushort4* dst;
    if (i < 262144) {            // w0: 1024x1024
      src = (const float4*)w0 + i;
      dst = (ushort4*)wb0 + i;
    } else if (i < 327680) {     // w1: 1024x256
      src = (const float4*)w1 + (i - 262144);
      dst = (ushort4*)wb1 + (i - 262144);
    } else {                     // w2: 1024x64
      src = (const float4*)w2 + (i - 327680);
      dst = (ushort4*)wb2 + (i - 327680);
    }
    float4 v = *src;
    ushort4 o;
    o.x = f2bf(v.x); o.y = f2bf(v.y); o.z = f2bf(v.z); o.w = f2bf(v.w);
    *dst = o;
  }
}

// ---------------------------------------------------------------------------
// Fused kernel B: gather used emb rows (fp32) -> compacted bf16 per cluster.
// blockIdx.z = cluster, hshift = 10 - 2*z.
// ---------------------------------------------------------------------------
__global__ __launch_bounds__(256) void gather_fused(
    const float* __restrict__ emb0, const float* __restrict__ emb1,
    const float* __restrict__ emb2, const int* __restrict__ blocal,
    const int* __restrict__ cnt, unsigned short* __restrict__ a0,
    unsigned short* __restrict__ a1, unsigned short* __restrict__ a2) {
  const int z = blockIdx.z;
  const int hshift = 10 - 2 * z;
  const float* emb = (z == 0) ? emb0 : (z == 1) ? emb1 : emb2;
  unsigned short* acomp = (z == 0) ? a0 : (z == 1) ? a1 : a2;
  const int* bl = blocal + z * NMAX;
  const int count = cnt[z];
  const int h4s = hshift - 2;  // log2(float4s per row)
  const int total = count << h4s;
  for (int i = blockIdx.x * 256 + threadIdx.x; i < total; i += gridDim.x * 256) {
    int row = i >> h4s;
    int k4 = i & ((1 << h4s) - 1);
    int loc = bl[row];
    float4 v = ((const float4*)(emb + ((size_t)loc << hshift)))[k4];
    ushort4 o;
    o.x = f2bf(v.x); o.y = f2bf(v.y); o.z = f2bf(v.z); o.w = f2bf(v.w);
    ((ushort4*)(acomp + ((size_t)row << hshift)))[k4] = o;
  }
}

// ---------------------------------------------------------------------------
// Fused per-cluster bf16 MFMA GEMM (m97 structure), blockIdx.z = cluster.
//   out[tok, n] = sum_k Acomp[m, k] * Wb[n, k]
// 128x128 tile, BK=32, 4 waves each owning a 64x64 quadrant as 4x4 MFMA
// 16x16x32 tiles. Staging via global_load_lds width=16 (LDS rows = 64B,
// linear in lane order -- required by the wave-uniform-base DMA).
// ---------------------------------------------------------------------------
template <int H>
__device__ __forceinline__ void gemm_body(
    const unsigned short* __restrict__ A, const unsigned short* __restrict__ B,
    int count, const int* __restrict__ bucket, float* __restrict__ out,
    unsigned short* As, unsigned short* Bs, int* rowTok) {
  const int m0 = blockIdx.y * 128;
  if (m0 >= count) return;
  const int n0 = blockIdx.x * 128;

  const int tid = threadIdx.x;
  const int wave = tid >> 6;
  const int lane = tid & 63;
  const int quad = lane >> 4;
  const int l16 = lane & 15;
  const int wm = wave & 1;   // quadrant row
  const int wn = wave >> 1;  // quadrant col

  if (tid < 128) {
    int m = m0 + tid;
    rowTok[tid] = (m < count) ? bucket[m] : -1;
  }

  floatx4 acc[4][4];
#pragma unroll
  for (int i = 0; i < 4; ++i)
#pragma unroll
    for (int j = 0; j < 4; ++j) acc[i][j] = (floatx4){0.f, 0.f, 0.f, 0.f};

  const char* Ab = (const char*)A;
  const char* Bb = (const char*)B;
  const int row_lo = tid >> 2;   // 0..63
  const int ck = tid & 3;        // 16B chunk within 64B row

  for (int k0 = 0; k0 < H; k0 += 32) {
    __syncthreads();
#pragma unroll
    for (int p = 0; p < 2; ++p) {
      const int row = p * 64 + row_lo;
      const void* ga = Ab + ((size_t)(m0 + row) * H + k0) * 2 + ck * 16;
      const void* gb = Bb + ((size_t)(n0 + row) * H + k0) * 2 + ck * 16;
      void* la = (char*)As + (p * 4096 + wave * 1024);  // wave-uniform base
      void* lb = (char*)Bs + (p * 4096 + wave * 1024);
      __builtin_amdgcn_global_load_lds(
          (const __attribute__((address_space(1))) void*)ga,
          (__attribute__((address_space(3))) void*)la, 16, 0, 0);
      __builtin_amdgcn_global_load_lds(
          (const __attribute__((address_space(1))) void*)gb,
          (__attribute__((address_space(3))) void*)lb, 16, 0, 0);
    }
    __syncthreads();

    short8 af[4], bf[4];
#pragma unroll
    for (int mi = 0; mi < 4; ++mi)
      af[mi] = *(const short8*)&As[(wm * 64 + mi * 16 + l16) * 32 + quad * 8];
#pragma unroll
    for (int ni = 0; ni < 4; ++ni)
      bf[ni] = *(const short8*)&Bs[(wn * 64 + ni * 16 + l16) * 32 + quad * 8];
#pragma unroll
    for (int mi = 0; mi < 4; ++mi)
#pragma unroll
      for (int ni = 0; ni < 4; ++ni)
        acc[mi][ni] = __builtin_amdgcn_mfma_f32_16x16x32_bf16(
            af[mi], bf[ni], acc[mi][ni], 0, 0, 0);
  }

  // epilogue: scatter rows to out[tok][*]  (C/D: col=lane&15, row=quad*4+reg)
  const int colBase = n0 + wn * 64 + l16;
#pragma unroll
  for (int mi = 0; mi < 4; ++mi) {
#pragma unroll
    for (int r = 0; r < 4; ++r) {
      int tok = rowTok[wm * 64 + mi * 16 + quad * 4 + r];
      if (tok >= 0) {
        float* o = out + (size_t)tok * DOUT + colBase;
#pragma unroll
        for (int ni = 0; ni < 4; ++ni) o[ni * 16] = acc[mi][ni][r];
      }
    }
  }
}

__global__ __launch_bounds__(256) void gemm_fused(
    const unsigned short* __restrict__ a0, const unsigned short* __restrict__ a1,
    const unsigned short* __restrict__ a2, const unsigned short* __restrict__ wb0,
    const unsigned short* __restrict__ wb1, const unsigned short* __restrict__ wb2,
    const int* __restrict__ cnt, const int* __restrict__ bucket,
    float* __restrict__ out) {
  __shared__ __align__(16) unsigned short As[128 * 32];  // [row][k], 64B rows
  __shared__ __align__(16) unsigned short Bs[128 * 32];
  __shared__ int rowTok[128];

  const int z = blockIdx.z;
  if (z == 0)
    gemm_body<1024>(a0, wb0, cnt[0], bucket + 0 * NMAX, out, As, Bs, rowTok);
  else if (z == 1)
    gemm_body<256>(a1, wb1, cnt[1], bucket + 1 * NMAX, out, As, Bs, rowTok);
  else
    gemm_body<64>(a2, wb2, cnt[2], bucket + 2 * NMAX, out, As, Bs, rowTok);
}

extern "C" void kernel_launch(void* const* d_in, const int* in_sizes, int n_in,
                              void* d_out, int out_size, void* d_ws, size_t ws_size,
                              hipStream_t stream) {
  const int* idx = (const int*)d_in[0];
  const float* emb0 = (const float*)d_in[1];
  const float* w0 = (const float*)d_in[2];
  const float* emb1 = (const float*)d_in[3];
  const float* w1 = (const float*)d_in[4];
  const float* emb2 = (const float*)d_in[5];
  const float* w2 = (const float*)d_in[6];
  float* out = (float*)d_out;
  const int N = in_sizes[0];  // 16384

  // ---- workspace layout ----
  char* ws = (char*)d_ws;
  int* cnt = (int*)ws;                              // 64 B
  int* bucket = (int*)(ws + 1024);                  // 3*NMAX ints
  int* blocal = bucket + 3 * NMAX;                  // 3*NMAX ints
  size_t off = 1024 + (size_t)6 * NMAX * 4;
  off = (off + 255) & ~(size_t)255;
  unsigned short* wb0 = (unsigned short*)(ws + off); off += (size_t)DOUT * 1024 * 2;
  unsigned short* wb1 = (unsigned short*)(ws + off); off += (size_t)DOUT * 256 * 2;
  unsigned short* wb2 = (unsigned short*)(ws + off); off += (size_t)DOUT * 64 * 2;
  off = (off + 255) & ~(size_t)255;
  unsigned short* a0 = (unsigned short*)(ws + off); off += (size_t)NMAX * 1024 * 2;
  unsigned short* a1 = (unsigned short*)(ws + off); off += (size_t)NMAX * 256 * 2;
  unsigned short* a2 = (unsigned short*)(ws + off); off += (size_t)NMAX * 64 * 2;

  hipMemsetAsync(cnt, 0, 16 * sizeof(int), stream);

  // classify (64 blocks) + weight cvt (1344 blocks)
  classify_cvt_kernel<<<64 + 1344, 256, 0, stream>>>(
      idx, cnt, bucket, blocal, N, w0, w1, w2, wb0, wb1, wb2);

  // gather all 3 clusters in one dispatch
  dim3 ggrid(512, 1, 3);
  gather_fused<<<ggrid, 256, 0, stream>>>(emb0, emb1, emb2, blocal, cnt, a0, a1, a2);

  // fused GEMM: z = cluster
  dim3 grid(DOUT / 128, NMAX / 128, 3);
  gemm_fused<<<grid, 256, 0, stream>>>(a0, a1, a2, wb0, wb1, wb2, cnt, bucket, out);
}

// Round 4
// 211.356 us; speedup vs baseline: 1.9801x; 1.0113x over previous
//
#include <hip/hip_runtime.h>
#include <stdint.h>

#define DOUT 1024
#define NMAX 16384

typedef __attribute__((ext_vector_type(8))) short short8;
typedef __attribute__((ext_vector_type(4))) float floatx4;

__device__ __forceinline__ unsigned short f2bf(float f) {
  union { float f; uint32_t u; } v;
  v.f = f;
  return (unsigned short)((v.u + 0x7FFFu + ((v.u >> 16) & 1u)) >> 16);  // RNE
}

// ---------------------------------------------------------------------------
// Fused kernel A: classify tokens (blocks 0..63) + convert all weights to
// bf16 (blocks 64..). Independent work, one dispatch.
// ---------------------------------------------------------------------------
__global__ __launch_bounds__(256) void classify_cvt_kernel(
    const int* __restrict__ idx, int* __restrict__ cnt,
    int* __restrict__ bucket, int* __restrict__ blocal, int N,
    const float* __restrict__ w0, const float* __restrict__ w1,
    const float* __restrict__ w2, unsigned short* __restrict__ wb0,
    unsigned short* __restrict__ wb1, unsigned short* __restrict__ wb2) {
  if (blockIdx.x < 64) {
    int n = blockIdx.x * 256 + threadIdx.x;
    int lane = threadIdx.x & 63;
    int c = -1, v = 0;
    if (n < N) {
      v = idx[n];
      c = (v < 20000) ? 0 : ((v < 40000) ? 1 : 2);
    }
#pragma unroll
    for (int k = 0; k < 3; ++k) {
      unsigned long long m = __ballot(c == k);
      if (c == k) {
        int leader = __ffsll((unsigned long long)m) - 1;
        int base = 0;
        if (lane == leader) base = atomicAdd(&cnt[k], (int)__popcll(m));
        base = __shfl(base, leader);
        int rank = (int)__popcll(m & ((1ull << (unsigned)lane) - 1ull));
        int lo = (k == 0) ? 0 : (k == 1) ? 20000 : 40000;
        bucket[k * NMAX + base + rank] = n;
        blocal[k * NMAX + base + rank] = v - lo;
      }
    }
  } else {
    // weight conversion: 344064 ushort4 units total
    int i = (blockIdx.x - 64) * 256 + threadIdx.x;
    if (i >= 344064) return;
    const float4* src;
    ushort4* dst;
    if (i < 262144) {            // w0: 1024x1024
      src = (const float4*)w0 + i;
      dst = (ushort4*)wb0 + i;
    } else if (i < 327680) {     // w1: 1024x256
      src = (const float4*)w1 + (i - 262144);
      dst = (ushort4*)wb1 + (i - 262144);
    } else {                     // w2: 1024x64
      src = (const float4*)w2 + (i - 327680);
      dst = (ushort4*)wb2 + (i - 327680);
    }
    float4 v = *src;
    ushort4 o;
    o.x = f2bf(v.x); o.y = f2bf(v.y); o.z = f2bf(v.z); o.w = f2bf(v.w);
    *dst = o;
  }
}

// ---------------------------------------------------------------------------
// Fused kernel B: gather used emb rows (fp32) -> compacted bf16 per cluster.
// blockIdx.z = cluster, hshift = 10 - 2*z.
// ---------------------------------------------------------------------------
__global__ __launch_bounds__(256) void gather_fused(
    const float* __restrict__ emb0, const float* __restrict__ emb1,
    const float* __restrict__ emb2, const int* __restrict__ blocal,
    const int* __restrict__ cnt, unsigned short* __restrict__ a0,
    unsigned short* __restrict__ a1, unsigned short* __restrict__ a2) {
  const int z = blockIdx.z;
  const int hshift = 10 - 2 * z;
  const float* emb = (z == 0) ? emb0 : (z == 1) ? emb1 : emb2;
  unsigned short* acomp = (z == 0) ? a0 : (z == 1) ? a1 : a2;
  const int* bl = blocal + z * NMAX;
  const int count = cnt[z];
  const int h4s = hshift - 2;  // log2(float4s per row)
  const int total = count << h4s;
  for (int i = blockIdx.x * 256 + threadIdx.x; i < total; i += gridDim.x * 256) {
    int row = i >> h4s;
    int k4 = i & ((1 << h4s) - 1);
    int loc = bl[row];
    float4 v = ((const float4*)(emb + ((size_t)loc << hshift)))[k4];
    ushort4 o;
    o.x = f2bf(v.x); o.y = f2bf(v.y); o.z = f2bf(v.z); o.w = f2bf(v.w);
    ((ushort4*)(acomp + ((size_t)row << hshift)))[k4] = o;
  }
}

// ---------------------------------------------------------------------------
// Fused per-cluster bf16 MFMA GEMM, blockIdx.z = cluster.
//   out[tok, n] = sum_k Acomp[m, k] * Wb[n, k]
// 64x128 tile (M x N), BK=32, 4 waves each owning a 32x64 quadrant as
// 2x4 MFMA 16x16x32 tiles. 2x the blocks of the 128x128 variant ->
// ~3.2 blocks/CU for cluster 0 (occupancy was the round-3 limiter).
// Staging via global_load_lds width=16; LDS dest = wave base + lane*16.
// ---------------------------------------------------------------------------
template <int H>
__device__ __forceinline__ void gemm_body(
    const unsigned short* __restrict__ A, const unsigned short* __restrict__ B,
    int count, const int* __restrict__ bucket, float* __restrict__ out,
    unsigned short* As, unsigned short* Bs, int* rowTok) {
  const int m0 = blockIdx.y * 64;
  if (m0 >= count) return;
  const int n0 = blockIdx.x * 128;

  const int tid = threadIdx.x;
  const int wave = tid >> 6;
  const int lane = tid & 63;
  const int quad = lane >> 4;
  const int l16 = lane & 15;
  const int wm = wave & 1;   // m-half (32 rows)
  const int wn = wave >> 1;  // n-half (64 cols)

  if (tid < 64) {
    int m = m0 + tid;
    rowTok[tid] = (m < count) ? bucket[m] : -1;
  }

  floatx4 acc[2][4];
#pragma unroll
  for (int i = 0; i < 2; ++i)
#pragma unroll
    for (int j = 0; j < 4; ++j) acc[i][j] = (floatx4){0.f, 0.f, 0.f, 0.f};

  const char* Ab = (const char*)A;
  const char* Bb = (const char*)B;
  const int row_lo = tid >> 2;   // 0..63
  const int ck = tid & 3;        // 16B chunk within 64B row

  for (int k0 = 0; k0 < H; k0 += 32) {
    __syncthreads();
    // A tile: 64 rows x 64B = 4KB, one pass
    {
      const void* ga = Ab + ((size_t)(m0 + row_lo) * H + k0) * 2 + ck * 16;
      void* la = (char*)As + wave * 1024;  // = base + lane*16 in lane order
      __builtin_amdgcn_global_load_lds(
          (const __attribute__((address_space(1))) void*)ga,
          (__attribute__((address_space(3))) void*)la, 16, 0, 0);
    }
    // B tile: 128 rows x 64B = 8KB, two passes
#pragma unroll
    for (int p = 0; p < 2; ++p) {
      const void* gb = Bb + ((size_t)(n0 + p * 64 + row_lo) * H + k0) * 2 + ck * 16;
      void* lb = (char*)Bs + (p * 4096 + wave * 1024);
      __builtin_amdgcn_global_load_lds(
          (const __attribute__((address_space(1))) void*)gb,
          (__attribute__((address_space(3))) void*)lb, 16, 0, 0);
    }
    __syncthreads();

    short8 af[2], bf[4];
#pragma unroll
    for (int mi = 0; mi < 2; ++mi)
      af[mi] = *(const short8*)&As[(wm * 32 + mi * 16 + l16) * 32 + quad * 8];
#pragma unroll
    for (int ni = 0; ni < 4; ++ni)
      bf[ni] = *(const short8*)&Bs[(wn * 64 + ni * 16 + l16) * 32 + quad * 8];
#pragma unroll
    for (int mi = 0; mi < 2; ++mi)
#pragma unroll
      for (int ni = 0; ni < 4; ++ni)
        acc[mi][ni] = __builtin_amdgcn_mfma_f32_16x16x32_bf16(
            af[mi], bf[ni], acc[mi][ni], 0, 0, 0);
  }

  // epilogue: scatter rows to out[tok][*]  (C/D: col=lane&15, row=quad*4+reg)
  const int colBase = n0 + wn * 64 + l16;
#pragma unroll
  for (int mi = 0; mi < 2; ++mi) {
#pragma unroll
    for (int r = 0; r < 4; ++r) {
      int tok = rowTok[wm * 32 + mi * 16 + quad * 4 + r];
      if (tok >= 0) {
        float* o = out + (size_t)tok * DOUT + colBase;
#pragma unroll
        for (int ni = 0; ni < 4; ++ni) o[ni * 16] = acc[mi][ni][r];
      }
    }
  }
}

__global__ __launch_bounds__(256) void gemm_fused(
    const unsigned short* __restrict__ a0, const unsigned short* __restrict__ a1,
    const unsigned short* __restrict__ a2, const unsigned short* __restrict__ wb0,
    const unsigned short* __restrict__ wb1, const unsigned short* __restrict__ wb2,
    const int* __restrict__ cnt, const int* __restrict__ bucket,
    float* __restrict__ out) {
  __shared__ __align__(16) unsigned short As[64 * 32];   // [row][k], 64B rows
  __shared__ __align__(16) unsigned short Bs[128 * 32];
  __shared__ int rowTok[64];

  const int z = blockIdx.z;
  if (z == 0)
    gemm_body<1024>(a0, wb0, cnt[0], bucket + 0 * NMAX, out, As, Bs, rowTok);
  else if (z == 1)
    gemm_body<256>(a1, wb1, cnt[1], bucket + 1 * NMAX, out, As, Bs, rowTok);
  else
    gemm_body<64>(a2, wb2, cnt[2], bucket + 2 * NMAX, out, As, Bs, rowTok);
}

extern "C" void kernel_launch(void* const* d_in, const int* in_sizes, int n_in,
                              void* d_out, int out_size, void* d_ws, size_t ws_size,
                              hipStream_t stream) {
  const int* idx = (const int*)d_in[0];
  const float* emb0 = (const float*)d_in[1];
  const float* w0 = (const float*)d_in[2];
  const float* emb1 = (const float*)d_in[3];
  const float* w1 = (const float*)d_in[4];
  const float* emb2 = (const float*)d_in[5];
  const float* w2 = (const float*)d_in[6];
  float* out = (float*)d_out;
  const int N = in_sizes[0];  // 16384

  // ---- workspace layout ----
  char* ws = (char*)d_ws;
  int* cnt = (int*)ws;                              // 64 B
  int* bucket = (int*)(ws + 1024);                  // 3*NMAX ints
  int* blocal = bucket + 3 * NMAX;                  // 3*NMAX ints
  size_t off = 1024 + (size_t)6 * NMAX * 4;
  off = (off + 255) & ~(size_t)255;
  unsigned short* wb0 = (unsigned short*)(ws + off); off += (size_t)DOUT * 1024 * 2;
  unsigned short* wb1 = (unsigned short*)(ws + off); off += (size_t)DOUT * 256 * 2;
  unsigned short* wb2 = (unsigned short*)(ws + off); off += (size_t)DOUT * 64 * 2;
  off = (off + 255) & ~(size_t)255;
  unsigned short* a0 = (unsigned short*)(ws + off); off += (size_t)NMAX * 1024 * 2;
  unsigned short* a1 = (unsigned short*)(ws + off); off += (size_t)NMAX * 256 * 2;
  unsigned short* a2 = (unsigned short*)(ws + off); off += (size_t)NMAX * 64 * 2;

  hipMemsetAsync(cnt, 0, 16 * sizeof(int), stream);

  // classify (64 blocks) + weight cvt (1344 blocks)
  classify_cvt_kernel<<<64 + 1344, 256, 0, stream>>>(
      idx, cnt, bucket, blocal, N, w0, w1, w2, wb0, wb1, wb2);

  // gather all 3 clusters in one dispatch
  dim3 ggrid(512, 1, 3);
  gather_fused<<<ggrid, 256, 0, stream>>>(emb0, emb1, emb2, blocal, cnt, a0, a1, a2);

  // fused GEMM: z = cluster, 64x128 tiles
  dim3 grid(DOUT / 128, NMAX / 64, 3);
  gemm_fused<<<grid, 256, 0, stream>>>(a0, a1, a2, wb0, wb1, wb2, cnt, bucket, out);
}

// Round 5
// 208.180 us; speedup vs baseline: 2.0103x; 1.0153x over previous
//
#include <hip/hip_runtime.h>
#include <stdint.h>

#define DOUT 1024
#define NMAX 16384

typedef __attribute__((ext_vector_type(8))) short short8;
typedef __attribute__((ext_vector_type(4))) float floatx4;

__device__ __forceinline__ unsigned short f2bf(float f) {
  union { float f; uint32_t u; } v;
  v.f = f;
  return (unsigned short)((v.u + 0x7FFFu + ((v.u >> 16) & 1u)) >> 16);  // RNE
}

// ---------------------------------------------------------------------------
// Fused kernel A: classify tokens (blocks 0..63) + convert all weights to
// bf16 (blocks 64..). Independent work, one dispatch.
// ---------------------------------------------------------------------------
__global__ __launch_bounds__(256) void classify_cvt_kernel(
    const int* __restrict__ idx, int* __restrict__ cnt,
    int* __restrict__ bucket, int* __restrict__ blocal, int N,
    const float* __restrict__ w0, const float* __restrict__ w1,
    const float* __restrict__ w2, unsigned short* __restrict__ wb0,
    unsigned short* __restrict__ wb1, unsigned short* __restrict__ wb2) {
  if (blockIdx.x < 64) {
    int n = blockIdx.x * 256 + threadIdx.x;
    int lane = threadIdx.x & 63;
    int c = -1, v = 0;
    if (n < N) {
      v = idx[n];
      c = (v < 20000) ? 0 : ((v < 40000) ? 1 : 2);
    }
#pragma unroll
    for (int k = 0; k < 3; ++k) {
      unsigned long long m = __ballot(c == k);
      if (c == k) {
        int leader = __ffsll((unsigned long long)m) - 1;
        int base = 0;
        if (lane == leader) base = atomicAdd(&cnt[k], (int)__popcll(m));
        base = __shfl(base, leader);
        int rank = (int)__popcll(m & ((1ull << (unsigned)lane) - 1ull));
        int lo = (k == 0) ? 0 : (k == 1) ? 20000 : 40000;
        bucket[k * NMAX + base + rank] = n;
        blocal[k * NMAX + base + rank] = v - lo;
      }
    }
  } else {
    // weight conversion: 344064 ushort4 units total
    int i = (blockIdx.x - 64) * 256 + threadIdx.x;
    if (i >= 344064) return;
    const float4* src;
    ushort4* dst;
    if (i < 262144) {            // w0: 1024x1024
      src = (const float4*)w0 + i;
      dst = (ushort4*)wb0 + i;
    } else if (i < 327680) {     // w1: 1024x256
      src = (const float4*)w1 + (i - 262144);
      dst = (ushort4*)wb1 + (i - 262144);
    } else {                     // w2: 1024x64
      src = (const float4*)w2 + (i - 327680);
      dst = (ushort4*)wb2 + (i - 327680);
    }
    float4 v = *src;
    ushort4 o;
    o.x = f2bf(v.x); o.y = f2bf(v.y); o.z = f2bf(v.z); o.w = f2bf(v.w);
    *dst = o;
  }
}

// ---------------------------------------------------------------------------
// Fused kernel B: gather used emb rows (fp32) -> compacted bf16 per cluster.
// blockIdx.z = cluster, hshift = 10 - 2*z.
// ---------------------------------------------------------------------------
__global__ __launch_bounds__(256) void gather_fused(
    const float* __restrict__ emb0, const float* __restrict__ emb1,
    const float* __restrict__ emb2, const int* __restrict__ blocal,
    const int* __restrict__ cnt, unsigned short* __restrict__ a0,
    unsigned short* __restrict__ a1, unsigned short* __restrict__ a2) {
  const int z = blockIdx.z;
  const int hshift = 10 - 2 * z;
  const float* emb = (z == 0) ? emb0 : (z == 1) ? emb1 : emb2;
  unsigned short* acomp = (z == 0) ? a0 : (z == 1) ? a1 : a2;
  const int* bl = blocal + z * NMAX;
  const int count = cnt[z];
  const int h4s = hshift - 2;  // log2(float4s per row)
  const int total = count << h4s;
  for (int i = blockIdx.x * 256 + threadIdx.x; i < total; i += gridDim.x * 256) {
    int row = i >> h4s;
    int k4 = i & ((1 << h4s) - 1);
    int loc = bl[row];
    float4 v = ((const float4*)(emb + ((size_t)loc << hshift)))[k4];
    ushort4 o;
    o.x = f2bf(v.x); o.y = f2bf(v.y); o.z = f2bf(v.z); o.w = f2bf(v.w);
    ((ushort4*)(acomp + ((size_t)row << hshift)))[k4] = o;
  }
}

// ---------------------------------------------------------------------------
// Fused per-cluster bf16 MFMA GEMM, blockIdx.z = cluster.
//   out[tok, n] = sum_k Acomp[m, k] * Wb[n, k]
// 64x128 tile (M x N), BK=64 as TWO stacked BK=32 sub-tiles (keeps the
// verified 64B-row LDS layout / fragment reads; halves barrier-drain count:
// H=1024 -> 16 K-iterations instead of 32). 4 waves, each a 32x64 quadrant
// (2x4 MFMA 16x16x32 per sub-tile). LDS = 24.8 KB -> occupancy stays
// VGPR-bound at ~4 blocks/CU.
// ---------------------------------------------------------------------------
template <int H>
__device__ __forceinline__ void gemm_body(
    const unsigned short* __restrict__ A, const unsigned short* __restrict__ B,
    int count, const int* __restrict__ bucket, float* __restrict__ out,
    unsigned short* As, unsigned short* Bs, int* rowTok) {
  const int m0 = blockIdx.y * 64;
  if (m0 >= count) return;
  const int n0 = blockIdx.x * 128;

  const int tid = threadIdx.x;
  const int wave = tid >> 6;
  const int lane = tid & 63;
  const int quad = lane >> 4;
  const int l16 = lane & 15;
  const int wm = wave & 1;   // m-half (32 rows)
  const int wn = wave >> 1;  // n-half (64 cols)

  if (tid < 64) {
    int m = m0 + tid;
    rowTok[tid] = (m < count) ? bucket[m] : -1;
  }

  floatx4 acc[2][4];
#pragma unroll
  for (int i = 0; i < 2; ++i)
#pragma unroll
    for (int j = 0; j < 4; ++j) acc[i][j] = (floatx4){0.f, 0.f, 0.f, 0.f};

  const char* Ab = (const char*)A;
  const char* Bb = (const char*)B;
  const int row_lo = tid >> 2;   // 0..63
  const int ck = tid & 3;        // 16B chunk within 64B sub-tile row

  for (int k0 = 0; k0 < H; k0 += 64) {
    __syncthreads();
    // A: 2 sub-tiles (k0, k0+32), each 64 rows x 64B = 4KB
#pragma unroll
    for (int t = 0; t < 2; ++t) {
      const void* ga = Ab + ((size_t)(m0 + row_lo) * H + k0 + t * 32) * 2 + ck * 16;
      void* la = (char*)As + (t * 4096 + wave * 1024);
      __builtin_amdgcn_global_load_lds(
          (const __attribute__((address_space(1))) void*)ga,
          (__attribute__((address_space(3))) void*)la, 16, 0, 0);
    }
    // B: 2 sub-tiles x 2 row-halves, each pass 64 rows x 64B = 4KB
#pragma unroll
    for (int t = 0; t < 2; ++t)
#pragma unroll
      for (int p = 0; p < 2; ++p) {
        const void* gb =
            Bb + ((size_t)(n0 + p * 64 + row_lo) * H + k0 + t * 32) * 2 + ck * 16;
        void* lb = (char*)Bs + (t * 8192 + p * 4096 + wave * 1024);
        __builtin_amdgcn_global_load_lds(
            (const __attribute__((address_space(1))) void*)gb,
            (__attribute__((address_space(3))) void*)lb, 16, 0, 0);
      }
    __syncthreads();

#pragma unroll
    for (int t = 0; t < 2; ++t) {
      short8 af[2], bf[4];
#pragma unroll
      for (int mi = 0; mi < 2; ++mi)
        af[mi] = *(const short8*)&As[t * 2048 + (wm * 32 + mi * 16 + l16) * 32 + quad * 8];
#pragma unroll
      for (int ni = 0; ni < 4; ++ni)
        bf[ni] = *(const short8*)&Bs[t * 4096 + (wn * 64 + ni * 16 + l16) * 32 + quad * 8];
#pragma unroll
      for (int mi = 0; mi < 2; ++mi)
#pragma unroll
        for (int ni = 0; ni < 4; ++ni)
          acc[mi][ni] = __builtin_amdgcn_mfma_f32_16x16x32_bf16(
              af[mi], bf[ni], acc[mi][ni], 0, 0, 0);
    }
  }

  // epilogue: scatter rows to out[tok][*]  (C/D: col=lane&15, row=quad*4+reg)
  const int colBase = n0 + wn * 64 + l16;
#pragma unroll
  for (int mi = 0; mi < 2; ++mi) {
#pragma unroll
    for (int r = 0; r < 4; ++r) {
      int tok = rowTok[wm * 32 + mi * 16 + quad * 4 + r];
      if (tok >= 0) {
        float* o = out + (size_t)tok * DOUT + colBase;
#pragma unroll
        for (int ni = 0; ni < 4; ++ni) o[ni * 16] = acc[mi][ni][r];
      }
    }
  }
}

__global__ __launch_bounds__(256) void gemm_fused(
    const unsigned short* __restrict__ a0, const unsigned short* __restrict__ a1,
    const unsigned short* __restrict__ a2, const unsigned short* __restrict__ wb0,
    const unsigned short* __restrict__ wb1, const unsigned short* __restrict__ wb2,
    const int* __restrict__ cnt, const int* __restrict__ bucket,
    float* __restrict__ out) {
  __shared__ __align__(16) unsigned short As[2 * 64 * 32];   // 2 sub-tiles, 64B rows
  __shared__ __align__(16) unsigned short Bs[2 * 128 * 32];
  __shared__ int rowTok[64];

  const int z = blockIdx.z;
  if (z == 0)
    gemm_body<1024>(a0, wb0, cnt[0], bucket + 0 * NMAX, out, As, Bs, rowTok);
  else if (z == 1)
    gemm_body<256>(a1, wb1, cnt[1], bucket + 1 * NMAX, out, As, Bs, rowTok);
  else
    gemm_body<64>(a2, wb2, cnt[2], bucket + 2 * NMAX, out, As, Bs, rowTok);
}

extern "C" void kernel_launch(void* const* d_in, const int* in_sizes, int n_in,
                              void* d_out, int out_size, void* d_ws, size_t ws_size,
                              hipStream_t stream) {
  const int* idx = (const int*)d_in[0];
  const float* emb0 = (const float*)d_in[1];
  const float* w0 = (const float*)d_in[2];
  const float* emb1 = (const float*)d_in[3];
  const float* w1 = (const float*)d_in[4];
  const float* emb2 = (const float*)d_in[5];
  const float* w2 = (const float*)d_in[6];
  float* out = (float*)d_out;
  const int N = in_sizes[0];  // 16384

  // ---- workspace layout ----
  char* ws = (char*)d_ws;
  int* cnt = (int*)ws;                              // 64 B
  int* bucket = (int*)(ws + 1024);                  // 3*NMAX ints
  int* blocal = bucket + 3 * NMAX;                  // 3*NMAX ints
  size_t off = 1024 + (size_t)6 * NMAX * 4;
  off = (off + 255) & ~(size_t)255;
  unsigned short* wb0 = (unsigned short*)(ws + off); off += (size_t)DOUT * 1024 * 2;
  unsigned short* wb1 = (unsigned short*)(ws + off); off += (size_t)DOUT * 256 * 2;
  unsigned short* wb2 = (unsigned short*)(ws + off); off += (size_t)DOUT * 64 * 2;
  off = (off + 255) & ~(size_t)255;
  unsigned short* a0 = (unsigned short*)(ws + off); off += (size_t)NMAX * 1024 * 2;
  unsigned short* a1 = (unsigned short*)(ws + off); off += (size_t)NMAX * 256 * 2;
  unsigned short* a2 = (unsigned short*)(ws + off); off += (size_t)NMAX * 64 * 2;

  hipMemsetAsync(cnt, 0, 16 * sizeof(int), stream);

  // classify (64 blocks) + weight cvt (1344 blocks)
  classify_cvt_kernel<<<64 + 1344, 256, 0, stream>>>(
      idx, cnt, bucket, blocal, N, w0, w1, w2, wb0, wb1, wb2);

  // gather all 3 clusters in one dispatch
  dim3 ggrid(512, 1, 3);
  gather_fused<<<ggrid, 256, 0, stream>>>(emb0, emb1, emb2, blocal, cnt, a0, a1, a2);

  // fused GEMM: z = cluster, 64x128 tiles, BK=64
  dim3 grid(DOUT / 128, NMAX / 64, 3);
  gemm_fused<<<grid, 256, 0, stream>>>(a0, a1, a2, wb0, wb1, wb2, cnt, bucket, out);
}

// Round 6
// 205.621 us; speedup vs baseline: 2.0353x; 1.0124x over previous
//
#include <hip/hip_runtime.h>
#include <hip/hip_bf16.h>
#include <stdint.h>

#define DOUT 1024
#define NMAX 16384

typedef __attribute__((ext_vector_type(8))) short short8;
typedef __attribute__((ext_vector_type(4))) float floatx4;

__device__ __forceinline__ unsigned short f2bf(float f) {
  union { float f; uint32_t u; } v;
  v.f = f;
  return (unsigned short)((v.u + 0x7FFFu + ((v.u >> 16) & 1u)) >> 16);  // RNE
}

// pack 8 fp32 -> 8 bf16 (RNE) using HW packed cvt
__device__ __forceinline__ short8 cvt8(float4 a, float4 b) {
  __hip_bfloat162 p0 = __float22bfloat162_rn(make_float2(a.x, a.y));
  __hip_bfloat162 p1 = __float22bfloat162_rn(make_float2(a.z, a.w));
  __hip_bfloat162 p2 = __float22bfloat162_rn(make_float2(b.x, b.y));
  __hip_bfloat162 p3 = __float22bfloat162_rn(make_float2(b.z, b.w));
  union { __hip_bfloat162 h[4]; short8 s; } u;
  u.h[0] = p0; u.h[1] = p1; u.h[2] = p2; u.h[3] = p3;
  return u.s;
}

// ---------------------------------------------------------------------------
// classify tokens (blocks 0..63) + convert weights to bf16 (blocks 64..).
// ---------------------------------------------------------------------------
__global__ __launch_bounds__(256) void classify_cvt_kernel(
    const int* __restrict__ idx, int* __restrict__ cnt,
    int* __restrict__ bucket, int* __restrict__ blocal, int N,
    const float* __restrict__ w0, const float* __restrict__ w1,
    const float* __restrict__ w2, unsigned short* __restrict__ wb0,
    unsigned short* __restrict__ wb1, unsigned short* __restrict__ wb2) {
  if (blockIdx.x < 64) {
    int n = blockIdx.x * 256 + threadIdx.x;
    int lane = threadIdx.x & 63;
    int c = -1, v = 0;
    if (n < N) {
      v = idx[n];
      c = (v < 20000) ? 0 : ((v < 40000) ? 1 : 2);
    }
#pragma unroll
    for (int k = 0; k < 3; ++k) {
      unsigned long long m = __ballot(c == k);
      if (c == k) {
        int leader = __ffsll((unsigned long long)m) - 1;
        int base = 0;
        if (lane == leader) base = atomicAdd(&cnt[k], (int)__popcll(m));
        base = __shfl(base, leader);
        int rank = (int)__popcll(m & ((1ull << (unsigned)lane) - 1ull));
        int lo = (k == 0) ? 0 : (k == 1) ? 20000 : 40000;
        bucket[k * NMAX + base + rank] = n;
        blocal[k * NMAX + base + rank] = v - lo;
      }
    }
  } else {
    int i = (blockIdx.x - 64) * 256 + threadIdx.x;
    if (i >= 344064) return;
    const float4* src;
    ushort4* dst;
    if (i < 262144) {            // w0: 1024x1024
      src = (const float4*)w0 + i;
      dst = (ushort4*)wb0 + i;
    } else if (i < 327680) {     // w1: 1024x256
      src = (const float4*)w1 + (i - 262144);
      dst = (ushort4*)wb1 + (i - 262144);
    } else {                     // w2: 1024x64
      src = (const float4*)w2 + (i - 327680);
      dst = (ushort4*)wb2 + (i - 327680);
    }
    float4 v = *src;
    ushort4 o;
    o.x = f2bf(v.x); o.y = f2bf(v.y); o.z = f2bf(v.z); o.w = f2bf(v.w);
    *dst = o;
  }
}

// ---------------------------------------------------------------------------
// Fused per-cluster bf16 MFMA GEMM with in-kernel A-gather.
//   out[tok, n] = sum_k emb[loc_m, k] * Wb[n, k]
// 64x128 tile (M x N), BK=64 as two BK=32 sub-tiles. A is gathered straight
// from the fp32 emb table: per sub-tile each thread loads 2x float4, packs
// to bf16 (v_cvt_pk_bf16_f32), ds_write_b128 into the same 64B-row LDS
// layout the MFMA fragment reads use. B staged via global_load_lds w=16.
// ---------------------------------------------------------------------------
template <int H>
__device__ __forceinline__ void gemm_body(
    const float* __restrict__ emb, const unsigned short* __restrict__ B,
    int count, const int* __restrict__ bucket, const int* __restrict__ blocal,
    float* __restrict__ out, unsigned short* As, unsigned short* Bs,
    int* rowTok, int* rowLoc) {
  const int m0 = blockIdx.y * 64;
  if (m0 >= count) return;
  const int n0 = blockIdx.x * 128;

  const int tid = threadIdx.x;
  const int wave = tid >> 6;
  const int lane = tid & 63;
  const int quad = lane >> 4;
  const int l16 = lane & 15;
  const int wm = wave & 1;   // m-half (32 rows)
  const int wn = wave >> 1;  // n-half (64 cols)

  if (tid < 64) {
    int m = m0 + tid;
    rowTok[tid] = (m < count) ? bucket[m] : -1;
    rowLoc[tid] = (m < count) ? blocal[m] : 0;
  }
  __syncthreads();

  floatx4 acc[2][4];
#pragma unroll
  for (int i = 0; i < 2; ++i)
#pragma unroll
    for (int j = 0; j < 4; ++j) acc[i][j] = (floatx4){0.f, 0.f, 0.f, 0.f};

  const char* Bb = (const char*)B;
  const int row_lo = tid >> 2;   // 0..63
  const int ck = tid & 3;        // 16B chunk within 64B sub-tile row

  // loop-invariant A source base for this thread's row
  const float* arow = emb + (size_t)rowLoc[row_lo] * H + ck * 8;

  for (int k0 = 0; k0 < H; k0 += 64) {
    __syncthreads();
    // A: gather fp32 -> bf16 -> LDS. 2 sub-tiles, each 64 rows x 32 k.
#pragma unroll
    for (int t = 0; t < 2; ++t) {
      const float* src = arow + k0 + t * 32;
      float4 v0 = *(const float4*)src;
      float4 v1 = *(const float4*)(src + 4);
      *(short8*)&As[t * 2048 + row_lo * 32 + ck * 8] = cvt8(v0, v1);
    }
    // B: 2 sub-tiles x 2 row-halves via global_load_lds (wave-uniform base)
#pragma unroll
    for (int t = 0; t < 2; ++t)
#pragma unroll
      for (int p = 0; p < 2; ++p) {
        const void* gb =
            Bb + ((size_t)(n0 + p * 64 + row_lo) * H + k0 + t * 32) * 2 + ck * 16;
        void* lb = (char*)Bs + (t * 8192 + p * 4096 + wave * 1024);
        __builtin_amdgcn_global_load_lds(
            (const __attribute__((address_space(1))) void*)gb,
            (__attribute__((address_space(3))) void*)lb, 16, 0, 0);
      }
    __syncthreads();

#pragma unroll
    for (int t = 0; t < 2; ++t) {
      short8 af[2], bf[4];
#pragma unroll
      for (int mi = 0; mi < 2; ++mi)
        af[mi] = *(const short8*)&As[t * 2048 + (wm * 32 + mi * 16 + l16) * 32 + quad * 8];
#pragma unroll
      for (int ni = 0; ni < 4; ++ni)
        bf[ni] = *(const short8*)&Bs[t * 4096 + (wn * 64 + ni * 16 + l16) * 32 + quad * 8];
#pragma unroll
      for (int mi = 0; mi < 2; ++mi)
#pragma unroll
        for (int ni = 0; ni < 4; ++ni)
          acc[mi][ni] = __builtin_amdgcn_mfma_f32_16x16x32_bf16(
              af[mi], bf[ni], acc[mi][ni], 0, 0, 0);
    }
  }

  // epilogue: scatter rows to out[tok][*]  (C/D: col=lane&15, row=quad*4+reg)
  const int colBase = n0 + wn * 64 + l16;
#pragma unroll
  for (int mi = 0; mi < 2; ++mi) {
#pragma unroll
    for (int r = 0; r < 4; ++r) {
      int tok = rowTok[wm * 32 + mi * 16 + quad * 4 + r];
      if (tok >= 0) {
        float* o = out + (size_t)tok * DOUT + colBase;
#pragma unroll
        for (int ni = 0; ni < 4; ++ni) o[ni * 16] = acc[mi][ni][r];
      }
    }
  }
}

__global__ __launch_bounds__(256) void gemm_fused(
    const float* __restrict__ emb0, const float* __restrict__ emb1,
    const float* __restrict__ emb2, const unsigned short* __restrict__ wb0,
    const unsigned short* __restrict__ wb1, const unsigned short* __restrict__ wb2,
    const int* __restrict__ cnt, const int* __restrict__ bucket,
    const int* __restrict__ blocal, float* __restrict__ out) {
  __shared__ __align__(16) unsigned short As[2 * 64 * 32];
  __shared__ __align__(16) unsigned short Bs[2 * 128 * 32];
  __shared__ int rowTok[64];
  __shared__ int rowLoc[64];

  const int z = blockIdx.z;
  if (z == 0)
    gemm_body<1024>(emb0, wb0, cnt[0], bucket + 0 * NMAX, blocal + 0 * NMAX,
                    out, As, Bs, rowTok, rowLoc);
  else if (z == 1)
    gemm_body<256>(emb1, wb1, cnt[1], bucket + 1 * NMAX, blocal + 1 * NMAX,
                   out, As, Bs, rowTok, rowLoc);
  else
    gemm_body<64>(emb2, wb2, cnt[2], bucket + 2 * NMAX, blocal + 2 * NMAX,
                  out, As, Bs, rowTok, rowLoc);
}

extern "C" void kernel_launch(void* const* d_in, const int* in_sizes, int n_in,
                              void* d_out, int out_size, void* d_ws, size_t ws_size,
                              hipStream_t stream) {
  const int* idx = (const int*)d_in[0];
  const float* emb0 = (const float*)d_in[1];
  const float* w0 = (const float*)d_in[2];
  const float* emb1 = (const float*)d_in[3];
  const float* w1 = (const float*)d_in[4];
  const float* emb2 = (const float*)d_in[5];
  const float* w2 = (const float*)d_in[6];
  float* out = (float*)d_out;
  const int N = in_sizes[0];  // 16384

  // ---- workspace layout ----
  char* ws = (char*)d_ws;
  int* cnt = (int*)ws;                              // 64 B
  int* bucket = (int*)(ws + 1024);                  // 3*NMAX ints
  int* blocal = bucket + 3 * NMAX;                  // 3*NMAX ints
  size_t off = 1024 + (size_t)6 * NMAX * 4;
  off = (off + 255) & ~(size_t)255;
  unsigned short* wb0 = (unsigned short*)(ws + off); off += (size_t)DOUT * 1024 * 2;
  unsigned short* wb1 = (unsigned short*)(ws + off); off += (size_t)DOUT * 256 * 2;
  unsigned short* wb2 = (unsigned short*)(ws + off); off += (size_t)DOUT * 64 * 2;

  hipMemsetAsync(cnt, 0, 16 * sizeof(int), stream);

  // classify (64 blocks) + weight cvt (1344 blocks)
  classify_cvt_kernel<<<64 + 1344, 256, 0, stream>>>(
      idx, cnt, bucket, blocal, N, w0, w1, w2, wb0, wb1, wb2);

  // fused GEMM with in-kernel A gather: z = cluster
  dim3 grid(DOUT / 128, NMAX / 64, 3);
  gemm_fused<<<grid, 256, 0, stream>>>(emb0, emb1, emb2, wb0, wb1, wb2,
                                       cnt, bucket, blocal, out);
}